// Round 1
// baseline (941.097 us; speedup 1.0000x reference)
//
#include <hip/hip_runtime.h>
#include <hip/hip_bf16.h>
#include <stdint.h>

#define B_ 2
#define N_ 4096
#define C_ 8
#define MAXDET 100
#define SCORE_THR 0.01f
#define NMS_THR 0.5f
#define NEGV -1e30f

// ---------- helpers ----------
__device__ __forceinline__ unsigned mono_key(float f) {
    unsigned u = __float_as_uint(f);
    return (u & 0x80000000u) ? ~u : (u | 0x80000000u);
}
__device__ __forceinline__ float mono_dec(unsigned m) {
    return (m & 0x80000000u) ? __uint_as_float(m ^ 0x80000000u)
                             : __uint_as_float(~m);
}

// ---------- 1) per-(b,c) bitonic sort ----------
// key = (mono(score_or_NEG) << 32) | (u32)~index   -> descending sort gives
// score desc, ties by lower index first (matches stable argsort of -scores).
__global__ __launch_bounds__(1024) void sort_kernel(
    const float* __restrict__ cls,       // (B,N,C)
    const float* __restrict__ boxes,     // (B,N,4)
    int* __restrict__ order,             // (B*C, N)
    float* __restrict__ sscores,         // (B*C, N)  sorted where(valid,s,NEG)
    float4* __restrict__ sboxes)         // (B*C, N)
{
    __shared__ unsigned long long k[N_];
    const int bc = blockIdx.x;
    const int b = bc >> 3, c = bc & 7;
    const int tid = threadIdx.x;

    for (int i = tid; i < N_; i += 1024) {
        float s = cls[((size_t)b * N_ + i) * C_ + c];
        float f = (s > SCORE_THR) ? s : NEGV;
        k[i] = ((unsigned long long)mono_key(f) << 32) | (unsigned)(~i);
    }
    __syncthreads();

    for (int size = 2; size <= N_; size <<= 1) {
        for (int stride = size >> 1; stride > 0; stride >>= 1) {
            for (int t = tid; t < N_ / 2; t += 1024) {
                int pos = 2 * t - (t & (stride - 1));
                int par = pos + stride;
                bool dir_desc = ((pos & size) == 0);
                unsigned long long a = k[pos], bb = k[par];
                // want a >= bb when dir_desc
                if ((a < bb) == dir_desc) { k[pos] = bb; k[par] = a; }
            }
            __syncthreads();
        }
    }

    const size_t base = (size_t)bc * N_;
    for (int p = tid; p < N_; p += 1024) {
        unsigned long long kk = k[p];
        int orig = (int)(~(unsigned)kk);
        order[base + p] = orig;
        sscores[base + p] = mono_dec((unsigned)(kk >> 32));
        sboxes[base + p] = ((const float4*)boxes)[(size_t)b * N_ + orig];
    }
}

// ---------- 2) suppression bitmask ----------
// mask[(bc*N + i)*64 + w] bit t set iff j = w*64+t, j > i, IoU(i,j) > thr.
__global__ __launch_bounds__(256) void mask_kernel(
    const float4* __restrict__ sboxes,
    unsigned long long* __restrict__ mask)
{
    const int bc = blockIdx.y;
    const int idx = blockIdx.x * 256 + threadIdx.x;   // 0 .. N*64-1
    const int i = idx >> 6;
    const int w = idx & 63;
    const size_t base = (size_t)bc * N_;
    const size_t out_idx = (base + i) * 64 + w;

    if (w * 64 + 63 <= i) { mask[out_idx] = 0ull; return; }

    float4 bi = sboxes[base + i];
    float ax1 = bi.x, ay1 = bi.y, ax2 = bi.z, ay2 = bi.w;
    float aarea = (ax2 - ax1) * (ay2 - ay1);

    unsigned long long bits = 0ull;
    #pragma unroll 8
    for (int t = 0; t < 64; t++) {
        int j = w * 64 + t;
        if (j <= i) continue;
        float4 bj = sboxes[base + j];
        float ix1 = fmaxf(ax1, bj.x);
        float iy1 = fmaxf(ay1, bj.y);
        float ix2 = fminf(ax2, bj.z);
        float iy2 = fminf(ay2, bj.w);
        float iw = fmaxf(ix2 - ix1, 0.0f);
        float ih = fmaxf(iy2 - iy1, 0.0f);
        float inter = iw * ih;
        float barea = (bj.z - bj.x) * (bj.w - bj.y);
        float uni = aarea + barea - inter;
        float iou = inter / fmaxf(uni, 1e-9f);
        if (iou > NMS_THR) bits |= (1ull << t);
    }
    mask[out_idx] = bits;
}

// ---------- 3) sequential greedy scan, one wave per (b,c) ----------
__global__ __launch_bounds__(64) void scan_kernel(
    const unsigned long long* __restrict__ mask,
    const int* __restrict__ order,
    const float* __restrict__ sscores,
    float* __restrict__ masked)          // (B, C*N) where(keep, s, NEG)
{
    const int bc = blockIdx.x;
    const int lane = threadIdx.x;
    const size_t base = (size_t)bc * N_;

    unsigned long long remv = 0ull;
    unsigned long long row_next = mask[base * 64 + lane];
    for (int i = 0; i < N_; i++) {
        unsigned long long row = row_next;
        if (i + 1 < N_) row_next = mask[(base + (i + 1)) * 64 + lane];
        int word = i >> 6, bit = i & 63;
        unsigned long long cur = __shfl(remv, word, 64);
        bool keep = !((cur >> bit) & 1ull);
        if (keep) remv |= row;   // row only has bits j>i, so bit i is final
    }

    // scatter keep decisions back to original anchor order
    const int b = bc >> 3, c = bc & 7;
    float* mout = masked + (size_t)b * C_ * N_ + (size_t)c * N_;
    for (int t = 0; t < 64; t++) {
        int p = lane * 64 + t;
        int orig = order[base + p];
        float sc = sscores[base + p];
        bool kp = !((remv >> t) & 1ull);
        mout[orig] = kp ? sc : NEGV;
    }
}

// ---------- 4) top-100 per image ----------
__global__ __launch_bounds__(1024) void topk_kernel(
    const float* __restrict__ masked,    // (B, C*N)
    unsigned long long* __restrict__ outkeys)  // (B, 128)
{
    const int b = blockIdx.x;
    const int tid = threadIdx.x;
    const int lane = tid & 63, wid = tid >> 6;
    const float* msk = masked + (size_t)b * C_ * N_;

    unsigned long long key[32];
    #pragma unroll
    for (int s = 0; s < 32; s++) {
        int flat = s * 1024 + tid;
        key[s] = ((unsigned long long)mono_key(msk[flat]) << 32)
                 | (unsigned)(~flat);
    }

    unsigned removed = 0u;
    unsigned long long lm = 0ull; int lpos = 0;
    #pragma unroll
    for (int s = 0; s < 32; s++) {
        if (key[s] > lm) { lm = key[s]; lpos = s; }
    }

    __shared__ unsigned long long warpmax[16];
    __shared__ unsigned long long sh_g;

    for (int kk = 0; kk < MAXDET; kk++) {
        unsigned long long wm = lm;
        #pragma unroll
        for (int off = 32; off >= 1; off >>= 1) {
            unsigned long long o = __shfl_xor(wm, off, 64);
            if (o > wm) wm = o;
        }
        if (lane == 0) warpmax[wid] = wm;
        __syncthreads();
        if (tid == 0) {
            unsigned long long g = warpmax[0];
            #pragma unroll
            for (int ww = 1; ww < 16; ww++)
                if (warpmax[ww] > g) g = warpmax[ww];
            sh_g = g;
            outkeys[b * 128 + kk] = g;
        }
        __syncthreads();
        unsigned long long g = sh_g;
        if (lm == g) {           // unique winner (index embedded in key)
            removed |= (1u << lpos);
            lm = 0ull; lpos = 0;
            #pragma unroll
            for (int s = 0; s < 32; s++) {
                unsigned long long v = (removed >> s) & 1u ? 0ull : key[s];
                if (v > lm) { lm = v; lpos = s; }
            }
        }
        __syncthreads();
    }
}

// ---------- 5) gather outputs ----------
// out layout (f32): boxes[2,100,4] | scores[2,100] | labels[2,100] |
//                   rot[2,100,3] | trans[2,100,3]   -> 2400 floats
__global__ __launch_bounds__(256) void gather_kernel(
    const unsigned long long* __restrict__ outkeys,
    const float* __restrict__ masked,
    const float* __restrict__ boxes,
    const float* __restrict__ rot,
    const float* __restrict__ trans,
    float* __restrict__ out)
{
    int t = blockIdx.x * 256 + threadIdx.x;
    if (t >= B_ * MAXDET) return;
    int b = t / MAXDET, kk = t % MAXDET;

    unsigned long long key = outkeys[b * 128 + kk];
    unsigned flat = ~(unsigned)key;
    float score = masked[(size_t)b * C_ * N_ + flat];
    bool ok = score > (NEGV * 0.5f);
    int c = flat >> 12;          // flat / N
    int n = flat & (N_ - 1);     // flat % N

    float* obox = out;                         // 800
    float* oscr = out + 800;                   // 200
    float* olab = out + 1000;                  // 200
    float* orot = out + 1200;                  // 600
    float* otrn = out + 1800;                  // 600

    #pragma unroll
    for (int d = 0; d < 4; d++)
        obox[b * 400 + kk * 4 + d] = ok ? boxes[((size_t)b * N_ + n) * 4 + d] : -1.0f;
    oscr[b * MAXDET + kk] = ok ? score : -1.0f;
    olab[b * MAXDET + kk] = ok ? (float)c : -1.0f;
    #pragma unroll
    for (int d = 0; d < 3; d++) {
        orot[b * 300 + kk * 3 + d] = ok ? rot[((size_t)b * N_ + n) * 3 + d] : -1.0f;
        otrn[b * 300 + kk * 3 + d] = ok ? trans[((size_t)b * N_ + n) * 3 + d] : -1.0f;
    }
}

extern "C" void kernel_launch(void* const* d_in, const int* in_sizes, int n_in,
                              void* d_out, int out_size, void* d_ws, size_t ws_size,
                              hipStream_t stream) {
    const float* boxes = (const float*)d_in[0];   // (2,4096,4)
    const float* cls   = (const float*)d_in[1];   // (2,4096,8)
    const float* rot   = (const float*)d_in[2];   // (2,4096,3)
    const float* trans = (const float*)d_in[3];   // (2,4096,3)
    float* out = (float*)d_out;

    // workspace carve (~35 MB)
    char* w = (char*)d_ws;
    unsigned long long* mask = (unsigned long long*)w;
    w += (size_t)B_ * C_ * N_ * 64 * sizeof(unsigned long long);   // 32 MB
    int* order = (int*)w;          w += (size_t)B_ * C_ * N_ * sizeof(int);
    float* sscores = (float*)w;    w += (size_t)B_ * C_ * N_ * sizeof(float);
    float4* sboxes = (float4*)w;   w += (size_t)B_ * C_ * N_ * sizeof(float4);
    float* masked = (float*)w;     w += (size_t)B_ * C_ * N_ * sizeof(float);
    unsigned long long* topkeys = (unsigned long long*)w;
    w += (size_t)B_ * 128 * sizeof(unsigned long long);

    sort_kernel<<<B_ * C_, 1024, 0, stream>>>(cls, boxes, order, sscores, sboxes);
    mask_kernel<<<dim3(N_ * 64 / 256, B_ * C_), 256, 0, stream>>>(sboxes, mask);
    scan_kernel<<<B_ * C_, 64, 0, stream>>>(mask, order, sscores, masked);
    topk_kernel<<<B_, 1024, 0, stream>>>(masked, topkeys);
    gather_kernel<<<1, 256, 0, stream>>>(topkeys, masked, boxes, rot, trans, out);
}

// Round 2
// 370.264 us; speedup vs baseline: 2.5417x; 2.5417x over previous
//
#include <hip/hip_runtime.h>
#include <hip/hip_bf16.h>
#include <stdint.h>

#define B_ 2
#define N_ 4096
#define C_ 8
#define MAXDET 100
#define SCORE_THR 0.01f
#define NMS_THR 0.5f
#define NEGV -1e30f

// ---------- helpers ----------
__device__ __forceinline__ unsigned mono_key(float f) {
    unsigned u = __float_as_uint(f);
    return (u & 0x80000000u) ? ~u : (u | 0x80000000u);
}
__device__ __forceinline__ float mono_dec(unsigned m) {
    return (m & 0x80000000u) ? __uint_as_float(m ^ 0x80000000u)
                             : __uint_as_float(~m);
}

// ---------- 1) per-(b,c) bitonic sort ----------
__global__ __launch_bounds__(1024) void sort_kernel(
    const float* __restrict__ cls,       // (B,N,C)
    const float* __restrict__ boxes,     // (B,N,4)
    int* __restrict__ order,             // (B*C, N)
    float* __restrict__ sscores,         // (B*C, N)
    float4* __restrict__ sboxes)         // (B*C, N)
{
    __shared__ unsigned long long k[N_];
    const int bc = blockIdx.x;
    const int b = bc >> 3, c = bc & 7;
    const int tid = threadIdx.x;

    for (int i = tid; i < N_; i += 1024) {
        float s = cls[((size_t)b * N_ + i) * C_ + c];
        float f = (s > SCORE_THR) ? s : NEGV;
        k[i] = ((unsigned long long)mono_key(f) << 32) | (unsigned)(~i);
    }
    __syncthreads();

    for (int size = 2; size <= N_; size <<= 1) {
        for (int stride = size >> 1; stride > 0; stride >>= 1) {
            for (int t = tid; t < N_ / 2; t += 1024) {
                int pos = 2 * t - (t & (stride - 1));
                int par = pos + stride;
                bool dir_desc = ((pos & size) == 0);
                unsigned long long a = k[pos], bb = k[par];
                if ((a < bb) == dir_desc) { k[pos] = bb; k[par] = a; }
            }
            __syncthreads();
        }
    }

    const size_t base = (size_t)bc * N_;
    for (int p = tid; p < N_; p += 1024) {
        unsigned long long kk = k[p];
        int orig = (int)(~(unsigned)kk);
        order[base + p] = orig;
        sscores[base + p] = mono_dec((unsigned)(kk >> 32));
        sboxes[base + p] = ((const float4*)boxes)[(size_t)b * N_ + orig];
    }
}

// ---------- 2) suppression bitmask, LDS-tiled ----------
// mask[(bc*N + i)*64 + w] bit t set iff j = w*64+t, j > i, IoU(i,j) > thr.
// Block = 256 thr handles 64 rows x all 64 words for one bc, in 4 column
// groups of 1024 boxes staged in LDS (reused by all 64 rows).
__global__ __launch_bounds__(256) void mask_kernel(
    const float4* __restrict__ sboxes,
    unsigned long long* __restrict__ mask)
{
    __shared__ float4 sb[1024];                 // 16 KB
    __shared__ float  sa[1024];                 // 4 KB
    __shared__ unsigned long long tile[64 * 17]; // padded, 8.7 KB

    const int bc = blockIdx.y;
    const int r0 = blockIdx.x * 64;
    const size_t base = (size_t)bc * N_;
    const int tid = threadIdx.x;
    const int lane = tid & 63;
    const int wave = tid >> 6;
    const int r = r0 + lane;
    const int wmin = r0 >> 6;    // words < wmin are entirely j <= i -> zero

    float4 bi = sboxes[base + r];
    float aarea = (bi.z - bi.x) * (bi.w - bi.y);

    for (int g = 0; g < 4; g++) {
        __syncthreads();                        // protect sb/tile reuse
        for (int j = tid; j < 1024; j += 256) {
            float4 bj = sboxes[base + g * 1024 + j];
            sb[j] = bj;
            sa[j] = (bj.z - bj.x) * (bj.w - bj.y);
        }
        __syncthreads();

        for (int wl = wave; wl < 16; wl += 4) {
            int w = g * 16 + wl;
            unsigned long long bits = 0ull;
            if (w >= wmin) {
                #pragma unroll 8
                for (int t = 0; t < 64; t++) {
                    int j = w * 64 + t;
                    float4 bj = sb[wl * 64 + t];
                    float barea = sa[wl * 64 + t];
                    float ix1 = fmaxf(bi.x, bj.x);
                    float iy1 = fmaxf(bi.y, bj.y);
                    float ix2 = fminf(bi.z, bj.z);
                    float iy2 = fminf(bi.w, bj.w);
                    float inter = fmaxf(ix2 - ix1, 0.0f) * fmaxf(iy2 - iy1, 0.0f);
                    float uni = fmaxf(aarea + barea - inter, 1e-9f);
                    float iou = inter / uni;     // IEEE div, matches np ref
                    if (j > r && iou > NMS_THR) bits |= (1ull << t);
                }
            }
            tile[lane * 17 + wl] = bits;
        }
        __syncthreads();

        for (int lin = tid; lin < 1024; lin += 256) {
            int rr = lin >> 4, wl = lin & 15;
            mask[(base + r0 + rr) * 64 + g * 16 + wl] = tile[rr * 17 + wl];
        }
    }
}

// ---------- 3) chunked greedy scan + per-class candidate emit ----------
// One wave per (b,c). Lane w owns removal-mask word w. 64 chunks of 64 sorted
// items; early exit after 128 candidates (only top-128 kept per class can
// reach the global top-100) or when all remaining items are invalid.
__global__ __launch_bounds__(64) void scan_kernel(
    const unsigned long long* __restrict__ mask,
    const int* __restrict__ order,
    const float* __restrict__ sscores,
    unsigned long long* __restrict__ cand)   // (B*C, 128) keys
{
    __shared__ unsigned long long shI[64];
    const int bc = blockIdx.x;
    const int lane = threadIdx.x;
    const size_t base = (size_t)bc * N_;
    const int cls = bc & 7;

    // init candidate slots (ws is poisoned)
    cand[bc * 128 + lane] = 0ull;
    cand[bc * 128 + 64 + lane] = 0ull;

    unsigned long long remv = 0ull;
    int cand_count = 0;

    for (int c = 0; c < 64 && cand_count < 128; c++) {
        const int p = c * 64 + lane;
        // intra-chunk 64x64 matrix: lane l holds word c of row c*64+l
        unsigned long long intra = mask[(base + p) * 64 + c];
        float sc = sscores[base + p];
        unsigned long long validb = __ballot(sc > -1e29f);
        if (validb == 0ull) break;   // sorted: everything later is invalid too

        __syncthreads();
        shI[lane] = intra;
        __syncthreads();

        unsigned long long curw = __shfl(remv, c, 64);  // removal word c
        unsigned long long kept = 0ull;
        #pragma unroll
        for (int t = 0; t < 64; t++) {
            unsigned long long bit = 1ull << t;
            if (!(curw & bit) && (validb & bit)) {   // unsuppressed & valid
                kept |= bit;
                curw |= shI[t];                      // its intra suppression
            }
        }

        // apply suppression of kept items to all words (coalesced loads)
        unsigned long long acc0 = 0ull, acc1 = 0ull;
        #pragma unroll 8
        for (int t = 0; t < 64; t += 2) {
            unsigned long long r0w = mask[(base + c * 64 + t) * 64 + lane];
            unsigned long long r1w = mask[(base + c * 64 + t + 1) * 64 + lane];
            if ((kept >> t) & 1ull) acc0 |= r0w;
            if ((kept >> (t + 1)) & 1ull) acc1 |= r1w;
        }
        remv |= acc0 | acc1;

        // emit candidates in sorted order
        if ((kept >> lane) & 1ull) {
            int rank = cand_count + __popcll(kept & ((1ull << lane) - 1ull));
            if (rank < 128) {
                int orig = order[base + p];
                unsigned flat = (unsigned)(cls * N_ + orig);
                cand[bc * 128 + rank] =
                    ((unsigned long long)mono_key(sc) << 32) | (unsigned)(~flat);
            }
        }
        cand_count += __popcll(kept);
    }
}

// ---------- 4) merge 8x128 candidates -> top-100, write outputs ----------
// out layout (f32): boxes[2,100,4] | scores[2,100] | labels[2,100] |
//                   rot[2,100,3] | trans[2,100,3]   -> 2400 floats
__global__ __launch_bounds__(1024) void merge_kernel(
    const unsigned long long* __restrict__ cand,
    const float* __restrict__ boxes,
    const float* __restrict__ rot,
    const float* __restrict__ trans,
    float* __restrict__ out)
{
    __shared__ unsigned long long sk[1024];
    const int b = blockIdx.x;
    const int tid = threadIdx.x;

    sk[tid] = cand[(size_t)b * 1024 + tid];   // (b*8+c)*128+slot == b*1024+tid

    for (int size = 2; size <= 1024; size <<= 1) {
        for (int stride = size >> 1; stride > 0; stride >>= 1) {
            __syncthreads();
            int partner = tid ^ stride;
            if (partner > tid) {
                bool desc = ((tid & size) == 0);
                unsigned long long a = sk[tid], bb = sk[partner];
                if ((a < bb) == desc) { sk[tid] = bb; sk[partner] = a; }
            }
        }
    }
    __syncthreads();

    if (tid < MAXDET) {
        unsigned long long key = sk[tid];
        float score = mono_dec((unsigned)(key >> 32));
        bool ok = score > (NEGV * 0.5f);     // NaN (padding) compares false
        unsigned flat = (~(unsigned)key) & 32767u;
        int c = flat >> 12;
        int n = flat & (N_ - 1);

        float* obox = out;                   // 800
        float* oscr = out + 800;             // 200
        float* olab = out + 1000;            // 200
        float* orot = out + 1200;            // 600
        float* otrn = out + 1800;            // 600

        #pragma unroll
        for (int d = 0; d < 4; d++)
            obox[b * 400 + tid * 4 + d] =
                ok ? boxes[((size_t)b * N_ + n) * 4 + d] : -1.0f;
        oscr[b * MAXDET + tid] = ok ? score : -1.0f;
        olab[b * MAXDET + tid] = ok ? (float)c : -1.0f;
        #pragma unroll
        for (int d = 0; d < 3; d++) {
            orot[b * 300 + tid * 3 + d] =
                ok ? rot[((size_t)b * N_ + n) * 3 + d] : -1.0f;
            otrn[b * 300 + tid * 3 + d] =
                ok ? trans[((size_t)b * N_ + n) * 3 + d] : -1.0f;
        }
    }
}

extern "C" void kernel_launch(void* const* d_in, const int* in_sizes, int n_in,
                              void* d_out, int out_size, void* d_ws, size_t ws_size,
                              hipStream_t stream) {
    const float* boxes = (const float*)d_in[0];   // (2,4096,4)
    const float* cls   = (const float*)d_in[1];   // (2,4096,8)
    const float* rot   = (const float*)d_in[2];   // (2,4096,3)
    const float* trans = (const float*)d_in[3];   // (2,4096,3)
    float* out = (float*)d_out;

    char* w = (char*)d_ws;
    unsigned long long* mask = (unsigned long long*)w;
    w += (size_t)B_ * C_ * N_ * 64 * sizeof(unsigned long long);   // 32 MB
    int* order = (int*)w;          w += (size_t)B_ * C_ * N_ * sizeof(int);
    float* sscores = (float*)w;    w += (size_t)B_ * C_ * N_ * sizeof(float);
    float4* sboxes = (float4*)w;   w += (size_t)B_ * C_ * N_ * sizeof(float4);
    unsigned long long* cand = (unsigned long long*)w;
    w += (size_t)B_ * C_ * 128 * sizeof(unsigned long long);

    sort_kernel<<<B_ * C_, 1024, 0, stream>>>(cls, boxes, order, sscores, sboxes);
    mask_kernel<<<dim3(64, B_ * C_), 256, 0, stream>>>(sboxes, mask);
    scan_kernel<<<B_ * C_, 64, 0, stream>>>(mask, order, sscores, cand);
    merge_kernel<<<B_, 1024, 0, stream>>>(cand, boxes, rot, trans, out);
}

// Round 3
// 189.411 us; speedup vs baseline: 4.9686x; 1.9548x over previous
//
#include <hip/hip_runtime.h>
#include <hip/hip_bf16.h>
#include <stdint.h>

#define B_ 2
#define N_ 4096
#define C_ 8
#define MAXDET 100
#define SCORE_THR 0.01f
#define NMS_THR 0.5f
#define NEGV -1e30f
#define CH 16              // chunks (x64 rows) covered by the fast path

// ---------- helpers ----------
__device__ __forceinline__ unsigned mono_key(float f) {
    unsigned u = __float_as_uint(f);
    return (u & 0x80000000u) ? ~u : (u | 0x80000000u);
}
__device__ __forceinline__ float mono_dec(unsigned m) {
    return (m & 0x80000000u) ? __uint_as_float(m ^ 0x80000000u)
                             : __uint_as_float(~m);
}

// ---------- 1a) sort phase A: per-1024-chunk bitonic (64 blocks) ----------
__global__ __launch_bounds__(512) void sortA_kernel(
    const float* __restrict__ cls,
    unsigned long long* __restrict__ keys)   // (B*C, N)
{
    __shared__ unsigned long long k[1024];
    const int q = blockIdx.x;        // quarter 0..3
    const int bc = blockIdx.y;
    const int b = bc >> 3, c = bc & 7;
    const int tid = threadIdx.x;
    const bool desc = ((q & 1) == 0);

    for (int li = tid; li < 1024; li += 512) {
        int i = q * 1024 + li;
        float s = cls[((size_t)b * N_ + i) * C_ + c];
        float f = (s > SCORE_THR) ? s : NEGV;
        k[li] = ((unsigned long long)mono_key(f) << 32) | (unsigned)(~i);
    }
    __syncthreads();

    for (int size = 2; size <= 1024; size <<= 1) {
        for (int stride = size >> 1; stride > 0; stride >>= 1) {
            int t = tid;
            int pos = 2 * t - (t & (stride - 1));
            int par = pos + stride;
            bool d = ((pos & size) == 0) ? desc : !desc;
            unsigned long long a = k[pos], bb = k[par];
            if ((a < bb) == d) { k[pos] = bb; k[par] = a; }
            __syncthreads();
        }
    }

    for (int li = tid; li < 1024; li += 512)
        keys[(size_t)bc * N_ + q * 1024 + li] = k[li];
}

// ---------- 1b) sort phase B: merge 2048 windows (32 blocks) ----------
__global__ __launch_bounds__(1024) void sortB_kernel(
    unsigned long long* __restrict__ keys)
{
    __shared__ unsigned long long k[2048];
    const int win = blockIdx.x;      // 0..1
    const int bc = blockIdx.y;
    const int tid = threadIdx.x;
    const bool desc = ((win & 1) == 0);
    const size_t base = (size_t)bc * N_ + win * 2048;

    k[tid] = keys[base + tid];
    k[tid + 1024] = keys[base + tid + 1024];
    __syncthreads();

    for (int stride = 1024; stride > 0; stride >>= 1) {
        int t = tid;
        int pos = 2 * t - (t & (stride - 1));
        int par = pos + stride;
        unsigned long long a = k[pos], bb = k[par];
        if ((a < bb) == desc) { k[pos] = bb; k[par] = a; }
        __syncthreads();
    }

    keys[base + tid] = k[tid];
    keys[base + tid + 1024] = k[tid + 1024];
}

// ---------- 1c) sort phase C: merge 4096 + emit (16 blocks) ----------
__global__ __launch_bounds__(1024) void sortC_kernel(
    const unsigned long long* __restrict__ keys,
    const float* __restrict__ boxes,
    int* __restrict__ order,
    float* __restrict__ sscores,
    float4* __restrict__ sboxes)
{
    __shared__ unsigned long long k[4096];
    const int bc = blockIdx.x;
    const int b = bc >> 3;
    const int tid = threadIdx.x;
    const size_t base = (size_t)bc * N_;

    for (int i = tid; i < 4096; i += 1024) k[i] = keys[base + i];
    __syncthreads();

    for (int stride = 2048; stride > 0; stride >>= 1) {
        for (int t = tid; t < 2048; t += 1024) {
            int pos = 2 * t - (t & (stride - 1));
            int par = pos + stride;
            unsigned long long a = k[pos], bb = k[par];
            if (a < bb) { k[pos] = bb; k[par] = a; }   // desc
        }
        __syncthreads();
    }

    for (int p = tid; p < 4096; p += 1024) {
        unsigned long long kk = k[p];
        int orig = (int)(~(unsigned)kk);
        order[base + p] = orig;
        sscores[base + p] = mono_dec((unsigned)(kk >> 32));
        sboxes[base + p] = ((const float4*)boxes)[(size_t)b * N_ + orig];
    }
}

// ---------- 2a) mask fast path: rows 0..CH*64-1, balanced fine grid ----------
// grid (wordgroup 0..15, chunk 0..CH-1, bc 0..15), 256 thr: each wave = 1 word.
__global__ __launch_bounds__(256) void mask_lo_kernel(
    const float4* __restrict__ sboxes,
    unsigned long long* __restrict__ mask)
{
    __shared__ float4 sb[256];
    const int wg = blockIdx.x;
    const int chunk = blockIdx.y;
    const int bc = blockIdx.z;
    const int tid = threadIdx.x;
    const int lane = tid & 63;
    const int wave = tid >> 6;
    const size_t base = (size_t)bc * N_;
    const int word = wg * 4 + wave;
    const int r = chunk * 64 + lane;

    sb[tid] = sboxes[base + wg * 256 + tid];
    __syncthreads();

    unsigned long long bits = 0ull;
    if (word >= chunk) {
        float4 bi = sboxes[base + r];
        float aarea = (bi.z - bi.x) * (bi.w - bi.y);
        unsigned long long rm =
            (word > chunk) ? ~0ull : ~((2ull << lane) - 1ull);
        #pragma unroll 8
        for (int t = 0; t < 64; t++) {
            float4 bj = sb[wave * 64 + t];
            float barea = (bj.z - bj.x) * (bj.w - bj.y);
            float ix1 = fmaxf(bi.x, bj.x);
            float iy1 = fmaxf(bi.y, bj.y);
            float ix2 = fminf(bi.z, bj.z);
            float iy2 = fminf(bi.w, bj.w);
            float inter = fmaxf(ix2 - ix1, 0.0f) * fmaxf(iy2 - iy1, 0.0f);
            float uni = fmaxf(aarea + barea - inter, 1e-9f);
            float iou = inter / uni;
            if (iou > NMS_THR) bits |= (1ull << t);
        }
        bits &= rm;
    }
    mask[(base + r) * 64 + word] = bits;
}

// ---------- 3a) greedy scan, chunks 0..CH-1, save state ----------
__global__ __launch_bounds__(64) void scan1_kernel(
    const unsigned long long* __restrict__ mask,
    const int* __restrict__ order,
    const float* __restrict__ sscores,
    unsigned long long* __restrict__ cand,      // (B*C, 128)
    unsigned long long* __restrict__ remv_s,    // (B*C, 64)
    int* __restrict__ cc_s,                     // (B*C)
    int* __restrict__ done_s)                   // (B*C)
{
    __shared__ unsigned long long shI[64];
    const int bc = blockIdx.x;
    const int lane = threadIdx.x;
    const size_t base = (size_t)bc * N_;
    const int cls = bc & 7;

    cand[bc * 128 + lane] = 0ull;
    cand[bc * 128 + 64 + lane] = 0ull;

    unsigned long long remv = 0ull;
    int cand_count = 0;
    bool finished = false;

    for (int c = 0; c < CH && cand_count < 128; c++) {
        const int p = c * 64 + lane;
        unsigned long long intra = mask[(base + p) * 64 + c];
        float sc = sscores[base + p];
        unsigned long long validb = __ballot(sc > -1e29f);
        if (validb == 0ull) { finished = true; break; }

        __syncthreads();
        shI[lane] = intra;
        __syncthreads();

        unsigned long long curw = __shfl(remv, c, 64);
        unsigned long long kept = 0ull;
        #pragma unroll
        for (int t = 0; t < 64; t++) {
            unsigned long long bit = 1ull << t;
            if (!(curw & bit) && (validb & bit)) {
                kept |= bit;
                curw |= shI[t];
            }
        }

        unsigned long long acc0 = 0ull, acc1 = 0ull;
        #pragma unroll 8
        for (int t = 0; t < 64; t += 2) {
            unsigned long long r0w = mask[(base + c * 64 + t) * 64 + lane];
            unsigned long long r1w = mask[(base + c * 64 + t + 1) * 64 + lane];
            if ((kept >> t) & 1ull) acc0 |= r0w;
            if ((kept >> (t + 1)) & 1ull) acc1 |= r1w;
        }
        remv |= acc0 | acc1;

        if ((kept >> lane) & 1ull) {
            int rank = cand_count + __popcll(kept & ((1ull << lane) - 1ull));
            if (rank < 128) {
                int orig = order[base + p];
                unsigned flat = (unsigned)(cls * N_ + orig);
                cand[bc * 128 + rank] =
                    ((unsigned long long)mono_key(sc) << 32) | (unsigned)(~flat);
            }
        }
        cand_count += __popcll(kept);
    }
    if (cand_count >= 128) finished = true;

    remv_s[bc * 64 + lane] = remv;
    if (lane == 0) { cc_s[bc] = cand_count; done_s[bc] = finished ? 1 : 0; }
}

// ---------- 2b) mask slow path: rows CH*64.., gated (normally no-op) -------
__global__ __launch_bounds__(256) void mask_hi_kernel(
    const float4* __restrict__ sboxes,
    unsigned long long* __restrict__ mask,
    const int* __restrict__ done_s)
{
    const int bc = blockIdx.y;
    if (done_s[bc]) return;

    __shared__ float4 sb[1024];
    __shared__ float  sa[1024];
    __shared__ unsigned long long tile[64 * 17];

    const int r0 = (CH + blockIdx.x) * 64;
    const size_t base = (size_t)bc * N_;
    const int tid = threadIdx.x;
    const int lane = tid & 63;
    const int wave = tid >> 6;
    const int r = r0 + lane;
    const int wmin = r0 >> 6;

    float4 bi = sboxes[base + r];
    float aarea = (bi.z - bi.x) * (bi.w - bi.y);

    for (int g = 0; g < 4; g++) {
        __syncthreads();
        for (int j = tid; j < 1024; j += 256) {
            float4 bj = sboxes[base + g * 1024 + j];
            sb[j] = bj;
            sa[j] = (bj.z - bj.x) * (bj.w - bj.y);
        }
        __syncthreads();

        for (int wl = wave; wl < 16; wl += 4) {
            int w = g * 16 + wl;
            unsigned long long bits = 0ull;
            if (w >= wmin) {
                #pragma unroll 8
                for (int t = 0; t < 64; t++) {
                    int j = w * 64 + t;
                    float4 bj = sb[wl * 64 + t];
                    float barea = sa[wl * 64 + t];
                    float ix1 = fmaxf(bi.x, bj.x);
                    float iy1 = fmaxf(bi.y, bj.y);
                    float ix2 = fminf(bi.z, bj.z);
                    float iy2 = fminf(bi.w, bj.w);
                    float inter = fmaxf(ix2 - ix1, 0.0f) * fmaxf(iy2 - iy1, 0.0f);
                    float uni = fmaxf(aarea + barea - inter, 1e-9f);
                    float iou = inter / uni;
                    if (j > r && iou > NMS_THR) bits |= (1ull << t);
                }
            }
            tile[lane * 17 + wl] = bits;
        }
        __syncthreads();

        for (int lin = tid; lin < 1024; lin += 256) {
            int rr = lin >> 4, wl = lin & 15;
            mask[(base + r0 + rr) * 64 + g * 16 + wl] = tile[rr * 17 + wl];
        }
    }
}

// ---------- 3b) scan resume, chunks CH..63, gated (normally no-op) ---------
__global__ __launch_bounds__(64) void scan2_kernel(
    const unsigned long long* __restrict__ mask,
    const int* __restrict__ order,
    const float* __restrict__ sscores,
    unsigned long long* __restrict__ cand,
    const unsigned long long* __restrict__ remv_s,
    const int* __restrict__ cc_s,
    const int* __restrict__ done_s)
{
    const int bc = blockIdx.x;
    if (done_s[bc]) return;

    __shared__ unsigned long long shI[64];
    const int lane = threadIdx.x;
    const size_t base = (size_t)bc * N_;
    const int cls = bc & 7;

    unsigned long long remv = remv_s[bc * 64 + lane];
    int cand_count = cc_s[bc];

    for (int c = CH; c < 64 && cand_count < 128; c++) {
        const int p = c * 64 + lane;
        unsigned long long intra = mask[(base + p) * 64 + c];
        float sc = sscores[base + p];
        unsigned long long validb = __ballot(sc > -1e29f);
        if (validb == 0ull) break;

        __syncthreads();
        shI[lane] = intra;
        __syncthreads();

        unsigned long long curw = __shfl(remv, c, 64);
        unsigned long long kept = 0ull;
        #pragma unroll
        for (int t = 0; t < 64; t++) {
            unsigned long long bit = 1ull << t;
            if (!(curw & bit) && (validb & bit)) {
                kept |= bit;
                curw |= shI[t];
            }
        }

        unsigned long long acc0 = 0ull, acc1 = 0ull;
        #pragma unroll 8
        for (int t = 0; t < 64; t += 2) {
            unsigned long long r0w = mask[(base + c * 64 + t) * 64 + lane];
            unsigned long long r1w = mask[(base + c * 64 + t + 1) * 64 + lane];
            if ((kept >> t) & 1ull) acc0 |= r0w;
            if ((kept >> (t + 1)) & 1ull) acc1 |= r1w;
        }
        remv |= acc0 | acc1;

        if ((kept >> lane) & 1ull) {
            int rank = cand_count + __popcll(kept & ((1ull << lane) - 1ull));
            if (rank < 128) {
                int orig = order[base + p];
                unsigned flat = (unsigned)(cls * N_ + orig);
                cand[bc * 128 + rank] =
                    ((unsigned long long)mono_key(sc) << 32) | (unsigned)(~flat);
            }
        }
        cand_count += __popcll(kept);
    }
}

// ---------- 4) merge 8x128 candidates -> top-100, write outputs ----------
__global__ __launch_bounds__(1024) void merge_kernel(
    const unsigned long long* __restrict__ cand,
    const float* __restrict__ boxes,
    const float* __restrict__ rot,
    const float* __restrict__ trans,
    float* __restrict__ out)
{
    __shared__ unsigned long long sk[1024];
    const int b = blockIdx.x;
    const int tid = threadIdx.x;

    sk[tid] = cand[(size_t)b * 1024 + tid];

    for (int size = 2; size <= 1024; size <<= 1) {
        for (int stride = size >> 1; stride > 0; stride >>= 1) {
            __syncthreads();
            int partner = tid ^ stride;
            if (partner > tid) {
                bool desc = ((tid & size) == 0);
                unsigned long long a = sk[tid], bb = sk[partner];
                if ((a < bb) == desc) { sk[tid] = bb; sk[partner] = a; }
            }
        }
    }
    __syncthreads();

    if (tid < MAXDET) {
        unsigned long long key = sk[tid];
        float score = mono_dec((unsigned)(key >> 32));
        bool ok = score > (NEGV * 0.5f);
        unsigned flat = (~(unsigned)key) & 32767u;
        int c = flat >> 12;
        int n = flat & (N_ - 1);

        float* obox = out;
        float* oscr = out + 800;
        float* olab = out + 1000;
        float* orot = out + 1200;
        float* otrn = out + 1800;

        #pragma unroll
        for (int d = 0; d < 4; d++)
            obox[b * 400 + tid * 4 + d] =
                ok ? boxes[((size_t)b * N_ + n) * 4 + d] : -1.0f;
        oscr[b * MAXDET + tid] = ok ? score : -1.0f;
        olab[b * MAXDET + tid] = ok ? (float)c : -1.0f;
        #pragma unroll
        for (int d = 0; d < 3; d++) {
            orot[b * 300 + tid * 3 + d] =
                ok ? rot[((size_t)b * N_ + n) * 3 + d] : -1.0f;
            otrn[b * 300 + tid * 3 + d] =
                ok ? trans[((size_t)b * N_ + n) * 3 + d] : -1.0f;
        }
    }
}

extern "C" void kernel_launch(void* const* d_in, const int* in_sizes, int n_in,
                              void* d_out, int out_size, void* d_ws, size_t ws_size,
                              hipStream_t stream) {
    const float* boxes = (const float*)d_in[0];
    const float* cls   = (const float*)d_in[1];
    const float* rot   = (const float*)d_in[2];
    const float* trans = (const float*)d_in[3];
    float* out = (float*)d_out;

    char* w = (char*)d_ws;
    unsigned long long* mask = (unsigned long long*)w;
    w += (size_t)B_ * C_ * N_ * 64 * sizeof(unsigned long long);   // 32 MB
    int* order = (int*)w;          w += (size_t)B_ * C_ * N_ * sizeof(int);
    float* sscores = (float*)w;    w += (size_t)B_ * C_ * N_ * sizeof(float);
    float4* sboxes = (float4*)w;   w += (size_t)B_ * C_ * N_ * sizeof(float4);
    unsigned long long* keys = (unsigned long long*)w;
    w += (size_t)B_ * C_ * N_ * sizeof(unsigned long long);
    unsigned long long* cand = (unsigned long long*)w;
    w += (size_t)B_ * C_ * 128 * sizeof(unsigned long long);
    unsigned long long* remv_s = (unsigned long long*)w;
    w += (size_t)B_ * C_ * 64 * sizeof(unsigned long long);
    int* cc_s = (int*)w;   w += B_ * C_ * sizeof(int);
    int* done_s = (int*)w; w += B_ * C_ * sizeof(int);

    sortA_kernel<<<dim3(4, B_ * C_), 512, 0, stream>>>(cls, keys);
    sortB_kernel<<<dim3(2, B_ * C_), 1024, 0, stream>>>(keys);
    sortC_kernel<<<B_ * C_, 1024, 0, stream>>>(keys, boxes, order, sscores, sboxes);
    mask_lo_kernel<<<dim3(16, CH, B_ * C_), 256, 0, stream>>>(sboxes, mask);
    scan1_kernel<<<B_ * C_, 64, 0, stream>>>(mask, order, sscores, cand,
                                             remv_s, cc_s, done_s);
    mask_hi_kernel<<<dim3(64 - CH, B_ * C_), 256, 0, stream>>>(sboxes, mask, done_s);
    scan2_kernel<<<B_ * C_, 64, 0, stream>>>(mask, order, sscores, cand,
                                             remv_s, cc_s, done_s);
    merge_kernel<<<B_, 1024, 0, stream>>>(cand, boxes, rot, trans, out);
}

// Round 4
// 135.789 us; speedup vs baseline: 6.9306x; 1.3949x over previous
//
#include <hip/hip_runtime.h>
#include <hip/hip_bf16.h>
#include <stdint.h>

#define B_ 2
#define N_ 4096
#define C_ 8
#define MAXDET 100
#define SCORE_THR 0.01f
#define NMS_THR 0.5f
#define NEGV -1e30f
#define CH 4               // chunks (x64 rows) covered by the fast path

// ---------- helpers ----------
__device__ __forceinline__ unsigned mono_key(float f) {
    unsigned u = __float_as_uint(f);
    return (u & 0x80000000u) ? ~u : (u | 0x80000000u);
}
__device__ __forceinline__ float mono_dec(unsigned m) {
    return (m & 0x80000000u) ? __uint_as_float(m ^ 0x80000000u)
                             : __uint_as_float(~m);
}
// exact predicate: RN32(inter/uni) > 0.5  (uni > 0)
// <=> (exact) 2*inter > uni*(1+2^-25)  <=> (inter+inter-uni) > uni*2^-25
// (Sterbenz-exact in the boundary band; sign/magnitude decides outside it)
__device__ __forceinline__ bool iou_gt_half(float inter, float uni) {
    return (inter + inter - uni) > uni * 0x1p-25f;
}

// ---------- 1a) sort phase A: per-1024-chunk bitonic (64 blocks) ----------
__global__ __launch_bounds__(512) void sortA_kernel(
    const float* __restrict__ cls,
    unsigned long long* __restrict__ keys)   // (B*C, N)
{
    __shared__ unsigned long long k[1024];
    const int q = blockIdx.x;        // quarter 0..3
    const int bc = blockIdx.y;
    const int b = bc >> 3, c = bc & 7;
    const int tid = threadIdx.x;
    const bool desc = ((q & 1) == 0);

    for (int li = tid; li < 1024; li += 512) {
        int i = q * 1024 + li;
        float s = cls[((size_t)b * N_ + i) * C_ + c];
        float f = (s > SCORE_THR) ? s : NEGV;
        k[li] = ((unsigned long long)mono_key(f) << 32) | (unsigned)(~i);
    }
    __syncthreads();

    for (int size = 2; size <= 1024; size <<= 1) {
        for (int stride = size >> 1; stride > 0; stride >>= 1) {
            int t = tid;
            int pos = 2 * t - (t & (stride - 1));
            int par = pos + stride;
            bool d = ((pos & size) == 0) ? desc : !desc;
            unsigned long long a = k[pos], bb = k[par];
            if ((a < bb) == d) { k[pos] = bb; k[par] = a; }
            __syncthreads();
        }
    }

    for (int li = tid; li < 1024; li += 512)
        keys[(size_t)bc * N_ + q * 1024 + li] = k[li];
}

// ---------- 1b) sort phases B+C fused: merge 2048 then 4096, emit ----------
__global__ __launch_bounds__(1024) void sortBC_kernel(
    const unsigned long long* __restrict__ keys,
    const float* __restrict__ boxes,
    int* __restrict__ order,
    float* __restrict__ sscores,
    float4* __restrict__ sboxes)
{
    __shared__ unsigned long long k[4096];
    const int bc = blockIdx.x;
    const int b = bc >> 3;
    const int tid = threadIdx.x;
    const size_t base = (size_t)bc * N_;

    for (int i = tid; i < 4096; i += 1024) k[i] = keys[base + i];
    __syncthreads();

    for (int size = 2048; size <= 4096; size <<= 1) {
        for (int stride = size >> 1; stride > 0; stride >>= 1) {
            for (int t = tid; t < 2048; t += 1024) {
                int pos = 2 * t - (t & (stride - 1));
                int par = pos + stride;
                bool d = ((pos & size) == 0);       // size=4096: always desc
                unsigned long long a = k[pos], bb = k[par];
                if ((a < bb) == d) { k[pos] = bb; k[par] = a; }
            }
            __syncthreads();
        }
    }

    for (int p = tid; p < 4096; p += 1024) {
        unsigned long long kk = k[p];
        int orig = (int)(~(unsigned)kk);
        order[base + p] = orig;
        sscores[base + p] = mono_dec((unsigned)(kk >> 32));
        sboxes[base + p] = ((const float4*)boxes)[(size_t)b * N_ + orig];
    }
}

// ---------- 2a) mask fast path: rows 0..CH*64-1, balanced fine grid --------
// grid (wordgroup 0..15, chunk 0..CH-1, bc 0..15), 256 thr: each wave = 1 word
__global__ __launch_bounds__(256) void mask_lo_kernel(
    const float4* __restrict__ sboxes,
    unsigned long long* __restrict__ mask)
{
    __shared__ float4 sb[256];
    __shared__ float  sa[256];
    const int wg = blockIdx.x;
    const int chunk = blockIdx.y;
    const int bc = blockIdx.z;
    const int tid = threadIdx.x;
    const int lane = tid & 63;
    const int wave = tid >> 6;
    const size_t base = (size_t)bc * N_;
    const int word = wg * 4 + wave;
    const int r = chunk * 64 + lane;

    float4 bs = sboxes[base + wg * 256 + tid];
    sb[tid] = bs;
    sa[tid] = (bs.z - bs.x) * (bs.w - bs.y);
    __syncthreads();

    unsigned long long bits = 0ull;
    if (word >= chunk) {
        float4 bi = sboxes[base + r];
        float aarea = (bi.z - bi.x) * (bi.w - bi.y);
        unsigned long long rm =
            (word > chunk) ? ~0ull : ~((2ull << lane) - 1ull);
        #pragma unroll 8
        for (int t = 0; t < 64; t++) {
            float4 bj = sb[wave * 64 + t];
            float barea = sa[wave * 64 + t];
            float ix1 = fmaxf(bi.x, bj.x);
            float iy1 = fmaxf(bi.y, bj.y);
            float ix2 = fminf(bi.z, bj.z);
            float iy2 = fminf(bi.w, bj.w);
            float inter = fmaxf(ix2 - ix1, 0.0f) * fmaxf(iy2 - iy1, 0.0f);
            float uni = fmaxf(aarea + barea - inter, 1e-9f);
            if (iou_gt_half(inter, uni)) bits |= (1ull << t);
        }
        bits &= rm;
    }
    mask[(base + r) * 64 + word] = bits;
}

// ---------- 3a) greedy scan, chunks 0..CH-1, save state ----------
__global__ __launch_bounds__(64) void scan1_kernel(
    const unsigned long long* __restrict__ mask,
    const int* __restrict__ order,
    const float* __restrict__ sscores,
    unsigned long long* __restrict__ cand,      // (B*C, 128)
    unsigned long long* __restrict__ remv_s,    // (B*C, 64)
    int* __restrict__ cc_s,                     // (B*C)
    int* __restrict__ done_s)                   // (B*C)
{
    __shared__ unsigned long long shI[64];
    const int bc = blockIdx.x;
    const int lane = threadIdx.x;
    const size_t base = (size_t)bc * N_;
    const int cls = bc & 7;

    cand[bc * 128 + lane] = 0ull;
    cand[bc * 128 + 64 + lane] = 0ull;

    unsigned long long remv = 0ull;
    int cand_count = 0;
    bool finished = false;

    for (int c = 0; c < CH; c++) {
        const int p = c * 64 + lane;
        unsigned long long intra = mask[(base + p) * 64 + c];
        float sc = sscores[base + p];
        unsigned long long validb = __ballot(sc > -1e29f);
        if (validb == 0ull) { finished = true; break; }

        __syncthreads();
        shI[lane] = intra;
        __syncthreads();

        unsigned long long curw = __shfl(remv, c, 64);
        unsigned long long kept = 0ull;
        #pragma unroll
        for (int t = 0; t < 64; t++) {
            unsigned long long bit = 1ull << t;
            if (!(curw & bit) && (validb & bit)) {
                kept |= bit;
                curw |= shI[t];
            }
        }

        // emit candidates in sorted order
        if ((kept >> lane) & 1ull) {
            int rank = cand_count + __popcll(kept & ((1ull << lane) - 1ull));
            if (rank < 128) {
                int orig = order[base + p];
                unsigned flat = (unsigned)(cls * N_ + orig);
                cand[bc * 128 + rank] =
                    ((unsigned long long)mono_key(sc) << 32) | (unsigned)(~flat);
            }
        }
        cand_count += __popcll(kept);
        if (cand_count >= 128) { finished = true; break; }  // state not needed

        // apply suppression of kept items (needed for next chunk / resume)
        unsigned long long acc0 = 0ull, acc1 = 0ull;
        #pragma unroll 8
        for (int t = 0; t < 64; t += 2) {
            unsigned long long r0w = mask[(base + c * 64 + t) * 64 + lane];
            unsigned long long r1w = mask[(base + c * 64 + t + 1) * 64 + lane];
            if ((kept >> t) & 1ull) acc0 |= r0w;
            if ((kept >> (t + 1)) & 1ull) acc1 |= r1w;
        }
        remv |= acc0 | acc1;
    }

    remv_s[bc * 64 + lane] = remv;
    if (lane == 0) { cc_s[bc] = cand_count; done_s[bc] = finished ? 1 : 0; }
}

// ---------- 2b) mask slow path: rows CH*64.., gated (normally no-op) -------
__global__ __launch_bounds__(256) void mask_hi_kernel(
    const float4* __restrict__ sboxes,
    unsigned long long* __restrict__ mask,
    const int* __restrict__ done_s)
{
    const int bc = blockIdx.y;
    if (done_s[bc]) return;

    __shared__ float4 sb[1024];
    __shared__ float  sa[1024];
    __shared__ unsigned long long tile[64 * 17];

    const int r0 = (CH + blockIdx.x) * 64;
    const size_t base = (size_t)bc * N_;
    const int tid = threadIdx.x;
    const int lane = tid & 63;
    const int wave = tid >> 6;
    const int r = r0 + lane;
    const int wmin = r0 >> 6;

    float4 bi = sboxes[base + r];
    float aarea = (bi.z - bi.x) * (bi.w - bi.y);

    for (int g = 0; g < 4; g++) {
        __syncthreads();
        for (int j = tid; j < 1024; j += 256) {
            float4 bj = sboxes[base + g * 1024 + j];
            sb[j] = bj;
            sa[j] = (bj.z - bj.x) * (bj.w - bj.y);
        }
        __syncthreads();

        for (int wl = wave; wl < 16; wl += 4) {
            int w = g * 16 + wl;
            unsigned long long bits = 0ull;
            if (w >= wmin) {
                #pragma unroll 8
                for (int t = 0; t < 64; t++) {
                    int j = w * 64 + t;
                    float4 bj = sb[wl * 64 + t];
                    float barea = sa[wl * 64 + t];
                    float ix1 = fmaxf(bi.x, bj.x);
                    float iy1 = fmaxf(bi.y, bj.y);
                    float ix2 = fminf(bi.z, bj.z);
                    float iy2 = fminf(bi.w, bj.w);
                    float inter = fmaxf(ix2 - ix1, 0.0f) * fmaxf(iy2 - iy1, 0.0f);
                    float uni = fmaxf(aarea + barea - inter, 1e-9f);
                    if (j > r && iou_gt_half(inter, uni)) bits |= (1ull << t);
                }
            }
            tile[lane * 17 + wl] = bits;
        }
        __syncthreads();

        for (int lin = tid; lin < 1024; lin += 256) {
            int rr = lin >> 4, wl = lin & 15;
            mask[(base + r0 + rr) * 64 + g * 16 + wl] = tile[rr * 17 + wl];
        }
    }
}

// ---------- 3b) scan resume, chunks CH..63, gated (normally no-op) ---------
__global__ __launch_bounds__(64) void scan2_kernel(
    const unsigned long long* __restrict__ mask,
    const int* __restrict__ order,
    const float* __restrict__ sscores,
    unsigned long long* __restrict__ cand,
    const unsigned long long* __restrict__ remv_s,
    const int* __restrict__ cc_s,
    const int* __restrict__ done_s)
{
    const int bc = blockIdx.x;
    if (done_s[bc]) return;

    __shared__ unsigned long long shI[64];
    const int lane = threadIdx.x;
    const size_t base = (size_t)bc * N_;
    const int cls = bc & 7;

    unsigned long long remv = remv_s[bc * 64 + lane];
    int cand_count = cc_s[bc];

    for (int c = CH; c < 64 && cand_count < 128; c++) {
        const int p = c * 64 + lane;
        unsigned long long intra = mask[(base + p) * 64 + c];
        float sc = sscores[base + p];
        unsigned long long validb = __ballot(sc > -1e29f);
        if (validb == 0ull) break;

        __syncthreads();
        shI[lane] = intra;
        __syncthreads();

        unsigned long long curw = __shfl(remv, c, 64);
        unsigned long long kept = 0ull;
        #pragma unroll
        for (int t = 0; t < 64; t++) {
            unsigned long long bit = 1ull << t;
            if (!(curw & bit) && (validb & bit)) {
                kept |= bit;
                curw |= shI[t];
            }
        }

        unsigned long long acc0 = 0ull, acc1 = 0ull;
        #pragma unroll 8
        for (int t = 0; t < 64; t += 2) {
            unsigned long long r0w = mask[(base + c * 64 + t) * 64 + lane];
            unsigned long long r1w = mask[(base + c * 64 + t + 1) * 64 + lane];
            if ((kept >> t) & 1ull) acc0 |= r0w;
            if ((kept >> (t + 1)) & 1ull) acc1 |= r1w;
        }
        remv |= acc0 | acc1;

        if ((kept >> lane) & 1ull) {
            int rank = cand_count + __popcll(kept & ((1ull << lane) - 1ull));
            if (rank < 128) {
                int orig = order[base + p];
                unsigned flat = (unsigned)(cls * N_ + orig);
                cand[bc * 128 + rank] =
                    ((unsigned long long)mono_key(sc) << 32) | (unsigned)(~flat);
            }
        }
        cand_count += __popcll(kept);
    }
}

// ---------- 4) merge 8 sorted 128-lists -> top-100, write outputs ----------
__global__ __launch_bounds__(1024) void merge_kernel(
    const unsigned long long* __restrict__ cand,
    const float* __restrict__ boxes,
    const float* __restrict__ rot,
    const float* __restrict__ trans,
    float* __restrict__ out)
{
    __shared__ unsigned long long sk[1024];
    const int b = blockIdx.x;
    const int tid = threadIdx.x;
    const int c = tid >> 7, s = tid & 127;

    // per-class lists are sorted desc; load odd classes reversed (asc)
    int src = (c & 1) ? (c * 128 + (127 - s)) : tid;
    sk[tid] = cand[(size_t)b * 1024 + src];

    // bitonic merge network only: 256 -> 512 -> 1024
    for (int size = 256; size <= 1024; size <<= 1) {
        for (int stride = size >> 1; stride > 0; stride >>= 1) {
            __syncthreads();
            int partner = tid ^ stride;
            if (partner > tid) {
                bool desc = ((tid & size) == 0);
                unsigned long long a = sk[tid], bb = sk[partner];
                if ((a < bb) == desc) { sk[tid] = bb; sk[partner] = a; }
            }
        }
    }
    __syncthreads();

    if (tid < MAXDET) {
        unsigned long long key = sk[tid];
        float score = mono_dec((unsigned)(key >> 32));
        bool ok = score > (NEGV * 0.5f);
        unsigned flat = (~(unsigned)key) & 32767u;
        int cc = flat >> 12;
        int n = flat & (N_ - 1);

        float* obox = out;
        float* oscr = out + 800;
        float* olab = out + 1000;
        float* orot = out + 1200;
        float* otrn = out + 1800;

        #pragma unroll
        for (int d = 0; d < 4; d++)
            obox[b * 400 + tid * 4 + d] =
                ok ? boxes[((size_t)b * N_ + n) * 4 + d] : -1.0f;
        oscr[b * MAXDET + tid] = ok ? score : -1.0f;
        olab[b * MAXDET + tid] = ok ? (float)cc : -1.0f;
        #pragma unroll
        for (int d = 0; d < 3; d++) {
            orot[b * 300 + tid * 3 + d] =
                ok ? rot[((size_t)b * N_ + n) * 3 + d] : -1.0f;
            otrn[b * 300 + tid * 3 + d] =
                ok ? trans[((size_t)b * N_ + n) * 3 + d] : -1.0f;
        }
    }
}

extern "C" void kernel_launch(void* const* d_in, const int* in_sizes, int n_in,
                              void* d_out, int out_size, void* d_ws, size_t ws_size,
                              hipStream_t stream) {
    const float* boxes = (const float*)d_in[0];
    const float* cls   = (const float*)d_in[1];
    const float* rot   = (const float*)d_in[2];
    const float* trans = (const float*)d_in[3];
    float* out = (float*)d_out;

    char* w = (char*)d_ws;
    unsigned long long* mask = (unsigned long long*)w;
    w += (size_t)B_ * C_ * N_ * 64 * sizeof(unsigned long long);   // 32 MB
    int* order = (int*)w;          w += (size_t)B_ * C_ * N_ * sizeof(int);
    float* sscores = (float*)w;    w += (size_t)B_ * C_ * N_ * sizeof(float);
    float4* sboxes = (float4*)w;   w += (size_t)B_ * C_ * N_ * sizeof(float4);
    unsigned long long* keys = (unsigned long long*)w;
    w += (size_t)B_ * C_ * N_ * sizeof(unsigned long long);
    unsigned long long* cand = (unsigned long long*)w;
    w += (size_t)B_ * C_ * 128 * sizeof(unsigned long long);
    unsigned long long* remv_s = (unsigned long long*)w;
    w += (size_t)B_ * C_ * 64 * sizeof(unsigned long long);
    int* cc_s = (int*)w;   w += B_ * C_ * sizeof(int);
    int* done_s = (int*)w; w += B_ * C_ * sizeof(int);

    sortA_kernel<<<dim3(4, B_ * C_), 512, 0, stream>>>(cls, keys);
    sortBC_kernel<<<B_ * C_, 1024, 0, stream>>>(keys, boxes, order, sscores, sboxes);
    mask_lo_kernel<<<dim3(16, CH, B_ * C_), 256, 0, stream>>>(sboxes, mask);
    scan1_kernel<<<B_ * C_, 64, 0, stream>>>(mask, order, sscores, cand,
                                             remv_s, cc_s, done_s);
    mask_hi_kernel<<<dim3(64 - CH, B_ * C_), 256, 0, stream>>>(sboxes, mask, done_s);
    scan2_kernel<<<B_ * C_, 64, 0, stream>>>(mask, order, sscores, cand,
                                             remv_s, cc_s, done_s);
    merge_kernel<<<B_, 1024, 0, stream>>>(cand, boxes, rot, trans, out);
}